// Round 14
// baseline (75.991 us; speedup 1.0000x reference)
//
#include <hip/hip_runtime.h>

#define NN 100000
#define NE 1600000
#define NBKT 391          // ceil(NN/256) buckets of 256 dst nodes
#define CAP 8192          // bucket capacity (mean 4092, +64 sigma)
#define TILE 4096         // edges per kP1 block
#define NTILE ((NE + TILE - 1) / TILE)   // 391
#define NEG 0.2f

// ---------------- kU: precompute u_s[8][4], u_d[8][4]; zero bcnt ----------------
__global__ __launch_bounds__(512) void kU_prep(
    const float* __restrict__ W1, const float* __restrict__ atts,
    const float* __restrict__ attd, float* __restrict__ us, float* __restrict__ ud,
    int* __restrict__ bcnt)
{
    int t = threadIdx.x;
    if (t < NBKT) bcnt[t] = 0;
    if (t < 64) {
        int half = t >> 5;             // 0: us, 1: ud
        int i = t & 31;
        int h = i >> 2, k = i & 3;
        const float* att = half ? attd : atts;
        float acc = 0.f;
        #pragma unroll
        for (int j = 0; j < 8; j++)
            acc += W1[k * 64 + h * 8 + j] * att[h * 8 + j];
        (half ? ud : us)[h * 4 + k] = acc;
    }
}

// ---------------- kP1: tiled bucket partition (LDS hist + batch reserve + coalesced out) ----------------
__global__ __launch_bounds__(1024) void kP1_tile(
    const int* __restrict__ ei, int* __restrict__ bcnt, unsigned* __restrict__ bpack)
{
    __shared__ unsigned sarr[TILE];          // 16 KB
    __shared__ int lh[512], lsc[512], lgb[512];
    int t = threadIdx.x;
    int e0 = blockIdx.x * TILE;
    int n = NE - e0; if (n > TILE) n = TILE;

    if (t < 512) lh[t] = 0;
    __syncthreads();
    for (int i = t; i < n; i += 1024) {
        int d = ei[NE + e0 + i];
        atomicAdd(&lh[d >> 8], 1);
    }
    __syncthreads();
    if (t < 512) lsc[t] = lh[t];
    __syncthreads();
    #pragma unroll
    for (int o = 1; o < 512; o <<= 1) {
        int u = 0;
        if (t < 512 && t >= o) u = lsc[t - o];
        __syncthreads();
        if (t < 512) lsc[t] += u;
        __syncthreads();
    }
    if (t < NBKT && lh[t] > 0) lgb[t] = atomicAdd(&bcnt[t], lh[t]);
    __syncthreads();
    if (t < 512) lh[t] = lsc[t] - lh[t];
    __syncthreads();
    for (int i = t; i < n; i += 1024) {
        int s = ei[e0 + i], d = ei[NE + e0 + i];
        int b = d >> 8;
        int pos = atomicAdd(&lh[b], 1);
        sarr[pos] = ((unsigned)s << 8) | (unsigned)(d & 255);
    }
    __syncthreads();
    int wave = t >> 6, lane = t & 63;
    for (int b = wave; b < NBKT; b += 16) {
        int start = (b == 0) ? 0 : lsc[b - 1];
        int cntb = lsc[b] - start;
        if (cntb == 0) continue;
        int gb = lgb[b];
        unsigned* dstp = &bpack[(size_t)b * CAP];
        for (int j = lane; j < cntb; j += 64) {
            int gpos = gb + j;
            if (gpos < CAP) dstp[gpos] = sarr[start + j];
        }
    }
}

// ---------------- kP2: per-bucket LDS counting sort -> rowsd + compact esrc + degree-sorted perm ----------------
__global__ __launch_bounds__(1024) void kP2_build(
    const int* __restrict__ bcnt, const unsigned* __restrict__ bpack,
    int2* __restrict__ rowsd, int* __restrict__ esrc, int* __restrict__ perm)
{
    __shared__ int lh[256], lsc[256], lcur[256];
    __shared__ int dcnt[256], dsc[256], dcur[256];
    __shared__ int sbs[512];
    __shared__ int sarr[CAP];
    int b = blockIdx.x;
    int t = threadIdx.x;
    // base = sum_{i<b} bcnt[i] : masked load + 9-step tree sum
    if (t < 512) sbs[t] = (t < b) ? bcnt[t] : 0;
    __syncthreads();
    #pragma unroll
    for (int o = 256; o > 0; o >>= 1) {
        if (t < o) sbs[t] += sbs[t + o];
        __syncthreads();
    }
    int base = sbs[0];
    int cnt = bcnt[b];
    if (cnt > CAP) cnt = CAP;
    const unsigned* bp = &bpack[(size_t)b * CAP];
    if (t < 256) { lh[t] = 0; dcnt[t] = 0; }
    __syncthreads();
    for (int i = t; i < cnt; i += 1024)
        atomicAdd(&lh[bp[i] & 255u], 1);
    __syncthreads();
    if (t < 256) lsc[t] = lh[t];
    __syncthreads();
    #pragma unroll
    for (int o = 1; o < 256; o <<= 1) {
        int u = 0;
        if (t < 256 && t >= o) u = lsc[t - o];
        __syncthreads();
        if (t < 256) lsc[t] += u;
        __syncthreads();
    }
    if (t < 256) {
        int ex = lsc[t] - lh[t];
        lcur[t] = ex;
        int node = b * 256 + t;
        if (node < NN) rowsd[node] = make_int2(base + ex, lh[t]);
        int dg = lh[t]; if (dg > 255) dg = 255;
        atomicAdd(&dcnt[dg], 1);
    }
    __syncthreads();
    // degree counting-sort scan
    if (t < 256) dsc[t] = dcnt[t];
    __syncthreads();
    #pragma unroll
    for (int o = 1; o < 256; o <<= 1) {
        int u = 0;
        if (t < 256 && t >= o) u = dsc[t - o];
        __syncthreads();
        if (t < 256) dsc[t] += u;
        __syncthreads();
    }
    if (t < 256) dcur[t] = dsc[t] - dcnt[t];
    __syncthreads();
    if (t < 256) {
        int dg = lh[t]; if (dg > 255) dg = 255;
        int pos = atomicAdd(&dcur[dg], 1);
        perm[b * 256 + pos] = t;        // local dst ids in increasing-degree order
    }
    // edge scatter
    for (int i = t; i < cnt; i += 1024) {
        unsigned u = bp[i];
        int pos = atomicAdd(&lcur[u & 255u], 1);
        sarr[pos] = (int)(u >> 8);
    }
    __syncthreads();
    for (int i = t; i < cnt; i += 1024)
        esrc[base + i] = sarr[i];
}

// ---------------- kE: layer-1: 8 lanes/dst, degree-sorted dst assignment, unroll 4 ----------------
__global__ __launch_bounds__(256) void kE_l1agg(
    const int2* __restrict__ rowsd, const int* __restrict__ esrc,
    const int* __restrict__ perm,
    const float* __restrict__ x, const float* __restrict__ us,
    const float* __restrict__ ud, const float* __restrict__ W1,
    const float* __restrict__ b1, const float* __restrict__ W2,
    float* __restrict__ h2)
{
    int t = threadIdx.x;
    int g = blockIdx.x;             // 0..3127
    int b = g >> 3, s = g & 7;      // bucket, slice
    int grp = t >> 3;               // 32 dst-groups per block
    int h   = t & 7;                // head
    int dl  = perm[b * 256 + s * 32 + grp];
    int dst = b * 256 + dl;
    if (dst >= NN) return;          // whole 8-lane group exits together

    int2 rd = rowsd[dst];
    int start = rd.x, m = rd.y;

    float4 u  = *reinterpret_cast<const float4*>(&us[h * 4]);
    float4 vd = *reinterpret_cast<const float4*>(&ud[h * 4]);
    float4 xd = *reinterpret_cast<const float4*>(&x[(size_t)dst * 4]);
    float adj = xd.x * vd.x + xd.y * vd.y + xd.z * vd.z + xd.w * vd.w;

    // self-loop (peeled)
    float a0 = fmaf(xd.x, u.x, fmaf(xd.y, u.y, fmaf(xd.z, u.z, fmaf(xd.w, u.w, adj))));
    a0 = fmaxf(a0, NEG * a0);
    float p0 = __expf(a0);
    float den = p0;
    float xa0 = p0 * xd.x, xa1 = p0 * xd.y, xa2 = p0 * xd.z, xa3 = p0 * xd.w;

    int j = 0;
    for (; j + 4 <= m; j += 4) {
        int s0 = esrc[start + j];
        int s1 = esrc[start + j + 1];
        int s2 = esrc[start + j + 2];
        int s3 = esrc[start + j + 3];
        float4 q0 = *reinterpret_cast<const float4*>(&x[(size_t)s0 * 4]);
        float4 q1 = *reinterpret_cast<const float4*>(&x[(size_t)s1 * 4]);
        float4 q2 = *reinterpret_cast<const float4*>(&x[(size_t)s2 * 4]);
        float4 q3 = *reinterpret_cast<const float4*>(&x[(size_t)s3 * 4]);
        float b0 = fmaf(q0.x, u.x, fmaf(q0.y, u.y, fmaf(q0.z, u.z, fmaf(q0.w, u.w, adj))));
        float b1v = fmaf(q1.x, u.x, fmaf(q1.y, u.y, fmaf(q1.z, u.z, fmaf(q1.w, u.w, adj))));
        float b2v = fmaf(q2.x, u.x, fmaf(q2.y, u.y, fmaf(q2.z, u.z, fmaf(q2.w, u.w, adj))));
        float b3v = fmaf(q3.x, u.x, fmaf(q3.y, u.y, fmaf(q3.z, u.z, fmaf(q3.w, u.w, adj))));
        b0  = fmaxf(b0,  NEG * b0);
        b1v = fmaxf(b1v, NEG * b1v);
        b2v = fmaxf(b2v, NEG * b2v);
        b3v = fmaxf(b3v, NEG * b3v);
        float pa = __expf(b0);
        float pb = __expf(b1v);
        float pc = __expf(b2v);
        float pd = __expf(b3v);
        den += (pa + pb) + (pc + pd);
        xa0 = fmaf(pa, q0.x, fmaf(pb, q1.x, fmaf(pc, q2.x, fmaf(pd, q3.x, xa0))));
        xa1 = fmaf(pa, q0.y, fmaf(pb, q1.y, fmaf(pc, q2.y, fmaf(pd, q3.y, xa1))));
        xa2 = fmaf(pa, q0.z, fmaf(pb, q1.z, fmaf(pc, q2.z, fmaf(pd, q3.z, xa2))));
        xa3 = fmaf(pa, q0.w, fmaf(pb, q1.w, fmaf(pc, q2.w, fmaf(pd, q3.w, xa3))));
    }
    for (; j < m; ++j) {
        int s0 = esrc[start + j];
        float4 q0 = *reinterpret_cast<const float4*>(&x[(size_t)s0 * 4]);
        float b0 = fmaf(q0.x, u.x, fmaf(q0.y, u.y, fmaf(q0.z, u.z, fmaf(q0.w, u.w, adj))));
        b0 = fmaxf(b0, NEG * b0);
        float pb = __expf(b0);
        den += pb;
        xa0 = fmaf(pb, q0.x, xa0);
        xa1 = fmaf(pb, q0.y, xa1);
        xa2 = fmaf(pb, q0.z, xa2);
        xa3 = fmaf(pb, q0.w, xa3);
    }

    // projection: lane handles its head's 8 channels c = h*8..h*8+7
    int c0 = h * 8;
    float4 w0l = *reinterpret_cast<const float4*>(&W1[c0]);
    float4 w0h = *reinterpret_cast<const float4*>(&W1[c0 + 4]);
    float4 w1l = *reinterpret_cast<const float4*>(&W1[64 + c0]);
    float4 w1h = *reinterpret_cast<const float4*>(&W1[64 + c0 + 4]);
    float4 w2l = *reinterpret_cast<const float4*>(&W1[128 + c0]);
    float4 w2h = *reinterpret_cast<const float4*>(&W1[128 + c0 + 4]);
    float4 w3l = *reinterpret_cast<const float4*>(&W1[192 + c0]);
    float4 w3h = *reinterpret_cast<const float4*>(&W1[192 + c0 + 4]);
    float4 bbl = *reinterpret_cast<const float4*>(&b1[c0]);
    float4 bbh = *reinterpret_cast<const float4*>(&b1[c0 + 4]);
    float4 wwl = *reinterpret_cast<const float4*>(&W2[c0]);
    float4 wwh = *reinterpret_cast<const float4*>(&W2[c0 + 4]);
    float inv = 1.f / (den + 1e-16f);

    float acc = 0.f;
    {
        float v;
        v = (xa0*w0l.x + xa1*w1l.x + xa2*w2l.x + xa3*w3l.x)*inv + bbl.x;
        v = v > 0.f ? v : (__expf(v) - 1.f);  acc += v * wwl.x;
        v = (xa0*w0l.y + xa1*w1l.y + xa2*w2l.y + xa3*w3l.y)*inv + bbl.y;
        v = v > 0.f ? v : (__expf(v) - 1.f);  acc += v * wwl.y;
        v = (xa0*w0l.z + xa1*w1l.z + xa2*w2l.z + xa3*w3l.z)*inv + bbl.z;
        v = v > 0.f ? v : (__expf(v) - 1.f);  acc += v * wwl.z;
        v = (xa0*w0l.w + xa1*w1l.w + xa2*w2l.w + xa3*w3l.w)*inv + bbl.w;
        v = v > 0.f ? v : (__expf(v) - 1.f);  acc += v * wwl.w;
        v = (xa0*w0h.x + xa1*w1h.x + xa2*w2h.x + xa3*w3h.x)*inv + bbh.x;
        v = v > 0.f ? v : (__expf(v) - 1.f);  acc += v * wwh.x;
        v = (xa0*w0h.y + xa1*w1h.y + xa2*w2h.y + xa3*w3h.y)*inv + bbh.y;
        v = v > 0.f ? v : (__expf(v) - 1.f);  acc += v * wwh.y;
        v = (xa0*w0h.z + xa1*w1h.z + xa2*w2h.z + xa3*w3h.z)*inv + bbh.z;
        v = v > 0.f ? v : (__expf(v) - 1.f);  acc += v * wwh.z;
        v = (xa0*w0h.w + xa1*w1h.w + xa2*w2h.w + xa3*w3h.w)*inv + bbh.w;
        v = v > 0.f ? v : (__expf(v) - 1.f);  acc += v * wwh.w;
    }
    // reduce 8 heads (width 8)
    acc += __shfl_xor(acc, 1, 8);
    acc += __shfl_xor(acc, 2, 8);
    acc += __shfl_xor(acc, 4, 8);
    if (h == 0) h2[dst] = acc;
}

// ---------------- kF: layer-2 aggregate + sigmoid (8 lanes per dst, unroll 4) ----------------
__global__ __launch_bounds__(256) void kF_l2agg(
    const int2* __restrict__ rowsd, const int* __restrict__ esrc,
    const float* __restrict__ h2, const float* __restrict__ as2,
    const float* __restrict__ ad2, const float* __restrict__ b2,
    float* __restrict__ out)
{
    int t = threadIdx.x;
    int grp = t >> 3;
    int sub = t & 7;
    int dst = blockIdx.x * 32 + grp;   // grid*32 == NN exactly
    int2 rd = rowsd[dst];
    int start = rd.x, end = rd.x + rd.y;
    float a_s = as2[0], a_d = ad2[0];
    float hdv = h2[dst];
    float hd = hdv * a_d;

    float den = 0.f, num = 0.f;
    if (sub == 0) {                           // self-loop
        float v = hdv * a_s + hd;
        v = fmaxf(v, NEG * v);
        float p = __expf(v);
        den = p;
        num = p * hdv;
    }
    int i = start + sub;
    for (; i + 24 < end; i += 32) {
        float hs0 = h2[esrc[i]];
        float hs1 = h2[esrc[i + 8]];
        float hs2 = h2[esrc[i + 16]];
        float hs3 = h2[esrc[i + 24]];
        float v0 = fmaf(hs0, a_s, hd);
        float v1 = fmaf(hs1, a_s, hd);
        float v2 = fmaf(hs2, a_s, hd);
        float v3 = fmaf(hs3, a_s, hd);
        v0 = fmaxf(v0, NEG * v0);
        v1 = fmaxf(v1, NEG * v1);
        v2 = fmaxf(v2, NEG * v2);
        v3 = fmaxf(v3, NEG * v3);
        float p0 = __expf(v0);
        float p1 = __expf(v1);
        float p2 = __expf(v2);
        float p3 = __expf(v3);
        den += (p0 + p1) + (p2 + p3);
        num = fmaf(p0, hs0, fmaf(p1, hs1, fmaf(p2, hs2, fmaf(p3, hs3, num))));
    }
    for (; i < end; i += 8) {
        float hs = h2[esrc[i]];
        float v = fmaf(hs, a_s, hd);
        v = fmaxf(v, NEG * v);
        float p = __expf(v);
        den += p;
        num = fmaf(p, hs, num);
    }
    den += __shfl_xor(den, 1, 8);
    num += __shfl_xor(num, 1, 8);
    den += __shfl_xor(den, 2, 8);
    num += __shfl_xor(num, 2, 8);
    den += __shfl_xor(den, 4, 8);
    num += __shfl_xor(num, 4, 8);
    if (sub == 0) {
        float v = num / (den + 1e-16f) + b2[0];
        out[dst] = 1.f / (1.f + __expf(-v));
    }
}

extern "C" void kernel_launch(void* const* d_in, const int* in_sizes, int n_in,
                              void* d_out, int out_size, void* d_ws, size_t ws_size,
                              hipStream_t stream) {
    const float* x     = (const float*)d_in[0];
    const int*   ei    = (const int*)d_in[1];
    const float* W1    = (const float*)d_in[2];
    const float* atts1 = (const float*)d_in[3];
    const float* attd1 = (const float*)d_in[4];
    const float* b1    = (const float*)d_in[5];
    const float* W2    = (const float*)d_in[6];
    const float* atts2 = (const float*)d_in[7];
    const float* attd2 = (const float*)d_in[8];
    const float* b2    = (const float*)d_in[9];
    float* out = (float*)d_out;

    float* w = (float*)d_ws;
    float* us = w;                       // 32
    float* ud = w + 32;                  // 32
    float* h2 = w + 64;                  // NN
    int*  ibase = (int*)(w + 64 + (size_t)NN);          // 8B-aligned
    int2* rowsd = (int2*)ibase;                          // NN int2
    int*  bcnt  = ibase + (size_t)2 * NN;                // NBKT (pad 512)
    int*  permb = ibase + (size_t)2 * NN + 512;          // NBKT*256
    int*  esrc  = permb + (size_t)NBKT * 256;            // NE (compact)
    unsigned* bpack = (unsigned*)(esrc + (size_t)NE);    // NBKT*CAP

    dim3 gE(NBKT * 8);                // 3128: bucket*8 slices of 32 dsts
    dim3 gF(NN / 32);                 // 3125 (exact)

    hipLaunchKernelGGL(kU_prep, dim3(1), dim3(512), 0, stream, W1, atts1, attd1, us, ud, bcnt);
    hipLaunchKernelGGL(kP1_tile, dim3(NTILE), dim3(1024), 0, stream, ei, bcnt, bpack);
    hipLaunchKernelGGL(kP2_build, dim3(NBKT), dim3(1024), 0, stream, bcnt, bpack, rowsd, esrc, permb);
    hipLaunchKernelGGL(kE_l1agg, gE, dim3(256), 0, stream, rowsd, esrc, permb, x, us, ud, W1, b1, W2, h2);
    hipLaunchKernelGGL(kF_l2agg, gF, dim3(256), 0, stream, rowsd, esrc, h2, atts2, attd2, b2, out);
}

// Round 15
// 71.031 us; speedup vs baseline: 1.0698x; 1.0698x over previous
//
#include <hip/hip_runtime.h>

#define NN 100000
#define NE 1600000
#define NBKT 391          // ceil(NN/256) buckets of 256 dst nodes
#define CAP 8192          // bucket capacity (mean 4092, +64 sigma)
#define TILE 4096         // edges per kP1 block
#define NTILE ((NE + TILE - 1) / TILE)   // 391
#define NEG 0.2f

// ---------------- kU: precompute u_s[8][4], u_d[8][4]; zero bcnt ----------------
__global__ __launch_bounds__(512) void kU_prep(
    const float* __restrict__ W1, const float* __restrict__ atts,
    const float* __restrict__ attd, float* __restrict__ us, float* __restrict__ ud,
    int* __restrict__ bcnt)
{
    int t = threadIdx.x;
    if (t < NBKT) bcnt[t] = 0;
    if (t < 64) {
        int half = t >> 5;             // 0: us, 1: ud
        int i = t & 31;
        int h = i >> 2, k = i & 3;
        const float* att = half ? attd : atts;
        float acc = 0.f;
        #pragma unroll
        for (int j = 0; j < 8; j++)
            acc += W1[k * 64 + h * 8 + j] * att[h * 8 + j];
        (half ? ud : us)[h * 4 + k] = acc;
    }
}

// ---------------- kP1: tiled bucket partition (LDS hist + batch reserve + coalesced out) ----------------
__global__ __launch_bounds__(1024) void kP1_tile(
    const int* __restrict__ ei, int* __restrict__ bcnt, unsigned* __restrict__ bpack)
{
    __shared__ unsigned sarr[TILE];          // 16 KB
    __shared__ int lh[512], lsc[512], lgb[512];
    int t = threadIdx.x;
    int e0 = blockIdx.x * TILE;
    int n = NE - e0; if (n > TILE) n = TILE;

    if (t < 512) lh[t] = 0;
    __syncthreads();
    for (int i = t; i < n; i += 1024) {
        int d = ei[NE + e0 + i];
        atomicAdd(&lh[d >> 8], 1);
    }
    __syncthreads();
    if (t < 512) lsc[t] = lh[t];
    __syncthreads();
    #pragma unroll
    for (int o = 1; o < 512; o <<= 1) {
        int u = 0;
        if (t < 512 && t >= o) u = lsc[t - o];
        __syncthreads();
        if (t < 512) lsc[t] += u;
        __syncthreads();
    }
    if (t < NBKT && lh[t] > 0) lgb[t] = atomicAdd(&bcnt[t], lh[t]);
    __syncthreads();
    if (t < 512) lh[t] = lsc[t] - lh[t];
    __syncthreads();
    for (int i = t; i < n; i += 1024) {
        int s = ei[e0 + i], d = ei[NE + e0 + i];
        int b = d >> 8;
        int pos = atomicAdd(&lh[b], 1);
        sarr[pos] = ((unsigned)s << 8) | (unsigned)(d & 255);
    }
    __syncthreads();
    int wave = t >> 6, lane = t & 63;
    for (int b = wave; b < NBKT; b += 16) {
        int start = (b == 0) ? 0 : lsc[b - 1];
        int cntb = lsc[b] - start;
        if (cntb == 0) continue;
        int gb = lgb[b];
        unsigned* dstp = &bpack[(size_t)b * CAP];
        for (int j = lane; j < cntb; j += 64) {
            int gpos = gb + j;
            if (gpos < CAP) dstp[gpos] = sarr[start + j];
        }
    }
}

// ---------------- kP2: per-bucket LDS counting sort -> rowsd + compact esrc ----------------
__global__ __launch_bounds__(1024) void kP2_build(
    const int* __restrict__ bcnt, const unsigned* __restrict__ bpack,
    int2* __restrict__ rowsd, int* __restrict__ esrc)
{
    __shared__ int lh[256], lsc[256], lcur[256];
    __shared__ int sbs[512];
    __shared__ int sarr[CAP];
    int b = blockIdx.x;
    int t = threadIdx.x;
    // base = sum_{i<b} bcnt[i] : masked load + 9-step tree sum
    if (t < 512) sbs[t] = (t < b) ? bcnt[t] : 0;
    __syncthreads();
    #pragma unroll
    for (int o = 256; o > 0; o >>= 1) {
        if (t < o) sbs[t] += sbs[t + o];
        __syncthreads();
    }
    int base = sbs[0];
    int cnt = bcnt[b];
    if (cnt > CAP) cnt = CAP;
    const unsigned* bp = &bpack[(size_t)b * CAP];
    if (t < 256) lh[t] = 0;
    __syncthreads();
    for (int i = t; i < cnt; i += 1024)
        atomicAdd(&lh[bp[i] & 255u], 1);
    __syncthreads();
    if (t < 256) lsc[t] = lh[t];
    __syncthreads();
    #pragma unroll
    for (int o = 1; o < 256; o <<= 1) {
        int u = 0;
        if (t < 256 && t >= o) u = lsc[t - o];
        __syncthreads();
        if (t < 256) lsc[t] += u;
        __syncthreads();
    }
    if (t < 256) {
        int ex = lsc[t] - lh[t];
        lcur[t] = ex;
        int node = b * 256 + t;
        if (node < NN) rowsd[node] = make_int2(base + ex, lh[t]);
    }
    __syncthreads();
    for (int i = t; i < cnt; i += 1024) {
        unsigned u = bp[i];
        int pos = atomicAdd(&lcur[u & 255u], 1);
        sarr[pos] = (int)(u >> 8);
    }
    __syncthreads();
    for (int i = t; i < cnt; i += 1024)
        esrc[base + i] = sarr[i];
}

// ---------------- kE: layer-1: 8 lanes/dst (8 heads), 8 dst/wave, unroll 4 ----------------
__global__ __launch_bounds__(256) void kE_l1agg(
    const int2* __restrict__ rowsd, const int* __restrict__ esrc,
    const float* __restrict__ x, const float* __restrict__ us,
    const float* __restrict__ ud, const float* __restrict__ W1,
    const float* __restrict__ b1, const float* __restrict__ W2,
    float* __restrict__ h2)
{
    int t = threadIdx.x;
    int grp = t >> 3;               // 32 dst-groups per block
    int h   = t & 7;                // head
    int dst = blockIdx.x * 32 + grp;   // grid*32 == NN exactly

    int2 rd = rowsd[dst];
    int start = rd.x, m = rd.y;

    float4 u  = *reinterpret_cast<const float4*>(&us[h * 4]);
    float4 vd = *reinterpret_cast<const float4*>(&ud[h * 4]);
    float4 xd = *reinterpret_cast<const float4*>(&x[(size_t)dst * 4]);
    float adj = xd.x * vd.x + xd.y * vd.y + xd.z * vd.z + xd.w * vd.w;

    // self-loop (peeled)
    float a0 = fmaf(xd.x, u.x, fmaf(xd.y, u.y, fmaf(xd.z, u.z, fmaf(xd.w, u.w, adj))));
    a0 = fmaxf(a0, NEG * a0);
    float p0 = __expf(a0);
    float den = p0;
    float xa0 = p0 * xd.x, xa1 = p0 * xd.y, xa2 = p0 * xd.z, xa3 = p0 * xd.w;

    int j = 0;
    for (; j + 4 <= m; j += 4) {
        int s0 = esrc[start + j];
        int s1 = esrc[start + j + 1];
        int s2 = esrc[start + j + 2];
        int s3 = esrc[start + j + 3];
        float4 q0 = *reinterpret_cast<const float4*>(&x[(size_t)s0 * 4]);
        float4 q1 = *reinterpret_cast<const float4*>(&x[(size_t)s1 * 4]);
        float4 q2 = *reinterpret_cast<const float4*>(&x[(size_t)s2 * 4]);
        float4 q3 = *reinterpret_cast<const float4*>(&x[(size_t)s3 * 4]);
        float b0 = fmaf(q0.x, u.x, fmaf(q0.y, u.y, fmaf(q0.z, u.z, fmaf(q0.w, u.w, adj))));
        float b1v = fmaf(q1.x, u.x, fmaf(q1.y, u.y, fmaf(q1.z, u.z, fmaf(q1.w, u.w, adj))));
        float b2v = fmaf(q2.x, u.x, fmaf(q2.y, u.y, fmaf(q2.z, u.z, fmaf(q2.w, u.w, adj))));
        float b3v = fmaf(q3.x, u.x, fmaf(q3.y, u.y, fmaf(q3.z, u.z, fmaf(q3.w, u.w, adj))));
        b0  = fmaxf(b0,  NEG * b0);
        b1v = fmaxf(b1v, NEG * b1v);
        b2v = fmaxf(b2v, NEG * b2v);
        b3v = fmaxf(b3v, NEG * b3v);
        float pa = __expf(b0);
        float pb = __expf(b1v);
        float pc = __expf(b2v);
        float pd = __expf(b3v);
        den += (pa + pb) + (pc + pd);
        xa0 = fmaf(pa, q0.x, fmaf(pb, q1.x, fmaf(pc, q2.x, fmaf(pd, q3.x, xa0))));
        xa1 = fmaf(pa, q0.y, fmaf(pb, q1.y, fmaf(pc, q2.y, fmaf(pd, q3.y, xa1))));
        xa2 = fmaf(pa, q0.z, fmaf(pb, q1.z, fmaf(pc, q2.z, fmaf(pd, q3.z, xa2))));
        xa3 = fmaf(pa, q0.w, fmaf(pb, q1.w, fmaf(pc, q2.w, fmaf(pd, q3.w, xa3))));
    }
    for (; j < m; ++j) {
        int s0 = esrc[start + j];
        float4 q0 = *reinterpret_cast<const float4*>(&x[(size_t)s0 * 4]);
        float b0 = fmaf(q0.x, u.x, fmaf(q0.y, u.y, fmaf(q0.z, u.z, fmaf(q0.w, u.w, adj))));
        b0 = fmaxf(b0, NEG * b0);
        float pb = __expf(b0);
        den += pb;
        xa0 = fmaf(pb, q0.x, xa0);
        xa1 = fmaf(pb, q0.y, xa1);
        xa2 = fmaf(pb, q0.z, xa2);
        xa3 = fmaf(pb, q0.w, xa3);
    }

    // projection: lane handles its head's 8 channels c = h*8..h*8+7
    int c0 = h * 8;
    float4 w0l = *reinterpret_cast<const float4*>(&W1[c0]);
    float4 w0h = *reinterpret_cast<const float4*>(&W1[c0 + 4]);
    float4 w1l = *reinterpret_cast<const float4*>(&W1[64 + c0]);
    float4 w1h = *reinterpret_cast<const float4*>(&W1[64 + c0 + 4]);
    float4 w2l = *reinterpret_cast<const float4*>(&W1[128 + c0]);
    float4 w2h = *reinterpret_cast<const float4*>(&W1[128 + c0 + 4]);
    float4 w3l = *reinterpret_cast<const float4*>(&W1[192 + c0]);
    float4 w3h = *reinterpret_cast<const float4*>(&W1[192 + c0 + 4]);
    float4 bbl = *reinterpret_cast<const float4*>(&b1[c0]);
    float4 bbh = *reinterpret_cast<const float4*>(&b1[c0 + 4]);
    float4 wwl = *reinterpret_cast<const float4*>(&W2[c0]);
    float4 wwh = *reinterpret_cast<const float4*>(&W2[c0 + 4]);
    float inv = 1.f / (den + 1e-16f);

    float acc = 0.f;
    {
        float v;
        v = (xa0*w0l.x + xa1*w1l.x + xa2*w2l.x + xa3*w3l.x)*inv + bbl.x;
        v = v > 0.f ? v : (__expf(v) - 1.f);  acc += v * wwl.x;
        v = (xa0*w0l.y + xa1*w1l.y + xa2*w2l.y + xa3*w3l.y)*inv + bbl.y;
        v = v > 0.f ? v : (__expf(v) - 1.f);  acc += v * wwl.y;
        v = (xa0*w0l.z + xa1*w1l.z + xa2*w2l.z + xa3*w3l.z)*inv + bbl.z;
        v = v > 0.f ? v : (__expf(v) - 1.f);  acc += v * wwl.z;
        v = (xa0*w0l.w + xa1*w1l.w + xa2*w2l.w + xa3*w3l.w)*inv + bbl.w;
        v = v > 0.f ? v : (__expf(v) - 1.f);  acc += v * wwl.w;
        v = (xa0*w0h.x + xa1*w1h.x + xa2*w2h.x + xa3*w3h.x)*inv + bbh.x;
        v = v > 0.f ? v : (__expf(v) - 1.f);  acc += v * wwh.x;
        v = (xa0*w0h.y + xa1*w1h.y + xa2*w2h.y + xa3*w3h.y)*inv + bbh.y;
        v = v > 0.f ? v : (__expf(v) - 1.f);  acc += v * wwh.y;
        v = (xa0*w0h.z + xa1*w1h.z + xa2*w2h.z + xa3*w3h.z)*inv + bbh.z;
        v = v > 0.f ? v : (__expf(v) - 1.f);  acc += v * wwh.z;
        v = (xa0*w0h.w + xa1*w1h.w + xa2*w2h.w + xa3*w3h.w)*inv + bbh.w;
        v = v > 0.f ? v : (__expf(v) - 1.f);  acc += v * wwh.w;
    }
    // reduce 8 heads (width 8)
    acc += __shfl_xor(acc, 1, 8);
    acc += __shfl_xor(acc, 2, 8);
    acc += __shfl_xor(acc, 4, 8);
    if (h == 0) h2[dst] = acc;
}

// ---------------- kF: layer-2 aggregate + sigmoid (8 lanes per dst, unroll 4) ----------------
__global__ __launch_bounds__(256) void kF_l2agg(
    const int2* __restrict__ rowsd, const int* __restrict__ esrc,
    const float* __restrict__ h2, const float* __restrict__ as2,
    const float* __restrict__ ad2, const float* __restrict__ b2,
    float* __restrict__ out)
{
    int t = threadIdx.x;
    int grp = t >> 3;
    int sub = t & 7;
    int dst = blockIdx.x * 32 + grp;   // grid*32 == NN exactly
    int2 rd = rowsd[dst];
    int start = rd.x, end = rd.x + rd.y;
    float a_s = as2[0], a_d = ad2[0];
    float hdv = h2[dst];
    float hd = hdv * a_d;

    float den = 0.f, num = 0.f;
    if (sub == 0) {                           // self-loop
        float v = hdv * a_s + hd;
        v = fmaxf(v, NEG * v);
        float p = __expf(v);
        den = p;
        num = p * hdv;
    }
    int i = start + sub;
    for (; i + 24 < end; i += 32) {
        float hs0 = h2[esrc[i]];
        float hs1 = h2[esrc[i + 8]];
        float hs2 = h2[esrc[i + 16]];
        float hs3 = h2[esrc[i + 24]];
        float v0 = fmaf(hs0, a_s, hd);
        float v1 = fmaf(hs1, a_s, hd);
        float v2 = fmaf(hs2, a_s, hd);
        float v3 = fmaf(hs3, a_s, hd);
        v0 = fmaxf(v0, NEG * v0);
        v1 = fmaxf(v1, NEG * v1);
        v2 = fmaxf(v2, NEG * v2);
        v3 = fmaxf(v3, NEG * v3);
        float p0 = __expf(v0);
        float p1 = __expf(v1);
        float p2 = __expf(v2);
        float p3 = __expf(v3);
        den += (p0 + p1) + (p2 + p3);
        num = fmaf(p0, hs0, fmaf(p1, hs1, fmaf(p2, hs2, fmaf(p3, hs3, num))));
    }
    for (; i < end; i += 8) {
        float hs = h2[esrc[i]];
        float v = fmaf(hs, a_s, hd);
        v = fmaxf(v, NEG * v);
        float p = __expf(v);
        den += p;
        num = fmaf(p, hs, num);
    }
    den += __shfl_xor(den, 1, 8);
    num += __shfl_xor(num, 1, 8);
    den += __shfl_xor(den, 2, 8);
    num += __shfl_xor(num, 2, 8);
    den += __shfl_xor(den, 4, 8);
    num += __shfl_xor(num, 4, 8);
    if (sub == 0) {
        float v = num / (den + 1e-16f) + b2[0];
        out[dst] = 1.f / (1.f + __expf(-v));
    }
}

extern "C" void kernel_launch(void* const* d_in, const int* in_sizes, int n_in,
                              void* d_out, int out_size, void* d_ws, size_t ws_size,
                              hipStream_t stream) {
    const float* x     = (const float*)d_in[0];
    const int*   ei    = (const int*)d_in[1];
    const float* W1    = (const float*)d_in[2];
    const float* atts1 = (const float*)d_in[3];
    const float* attd1 = (const float*)d_in[4];
    const float* b1    = (const float*)d_in[5];
    const float* W2    = (const float*)d_in[6];
    const float* atts2 = (const float*)d_in[7];
    const float* attd2 = (const float*)d_in[8];
    const float* b2    = (const float*)d_in[9];
    float* out = (float*)d_out;

    float* w = (float*)d_ws;
    float* us = w;                       // 32
    float* ud = w + 32;                  // 32
    float* h2 = w + 64;                  // NN
    int*  ibase = (int*)(w + 64 + (size_t)NN);          // 8B-aligned
    int2* rowsd = (int2*)ibase;                          // NN int2
    int*  bcnt  = ibase + (size_t)2 * NN;                // NBKT (pad 512)
    int*  esrc  = ibase + (size_t)2 * NN + 512;          // NE (compact)
    unsigned* bpack = (unsigned*)(esrc + (size_t)NE);    // NBKT*CAP

    dim3 gG(NN / 32);                 // 3125, 32 dst per block (exact)

    hipLaunchKernelGGL(kU_prep, dim3(1), dim3(512), 0, stream, W1, atts1, attd1, us, ud, bcnt);
    hipLaunchKernelGGL(kP1_tile, dim3(NTILE), dim3(1024), 0, stream, ei, bcnt, bpack);
    hipLaunchKernelGGL(kP2_build, dim3(NBKT), dim3(1024), 0, stream, bcnt, bpack, rowsd, esrc);
    hipLaunchKernelGGL(kE_l1agg, gG, dim3(256), 0, stream, rowsd, esrc, x, us, ud, W1, b1, W2, h2);
    hipLaunchKernelGGL(kF_l2agg, gG, dim3(256), 0, stream, rowsd, esrc, h2, atts2, attd2, b2, out);
}